// Round 9
// baseline (302.677 us; speedup 1.0000x reference)
//
#include <hip/hip_runtime.h>

#define IN_F 128
#define HID  16

// Bucket geometry: 256 buckets x 196 nodes covers N=50000.
// Bucket edge count ~ Binom(800k, 196/50k): mean 3136, sd ~56 -> CAP 4096 = +17 sigma.
#define NBKT 256
#define RANGE 196
#define BKT_CAP 4096
#define P1_EDGES 4096   // edges per pass-1 block (1024 threads x 4)

// ---------------------------------------------------------------------------
// Tiny precompute: CA = W2 @ Wmlp[:128], CB = W2 @ Wmlp[128:],
// cbias = b2@Wmlp[:128] + b2@Wmlp[128:] + bmlp.
// ---------------------------------------------------------------------------
__global__ void precompute_kernel(const float* __restrict__ W2,
                                  const float* __restrict__ b2,
                                  const float* __restrict__ Wmlp,
                                  const float* __restrict__ bmlp,
                                  float* __restrict__ CA,
                                  float* __restrict__ CB,
                                  float* __restrict__ cbias) {
    int t = threadIdx.x;
    int j = t >> 4, c = t & 15;
    float sa = 0.f, sb = 0.f;
    for (int k = 0; k < 128; ++k) {
        float w = W2[j * 128 + k];
        sa += w * Wmlp[k * 16 + c];
        sb += w * Wmlp[(128 + k) * 16 + c];
    }
    CA[j * 16 + c] = sa;
    CB[j * 16 + c] = sb;
    if (j == 0) {
        float s = bmlp[c];
        for (int k = 0; k < 128; ++k)
            s += b2[k] * (Wmlp[k * 16 + c] + Wmlp[(128 + k) * 16 + c]);
        cbias[c] = s;
    }
}

// ---------------------------------------------------------------------------
// y = x @ W1   ([N,128] @ [128,16] -> [N,16])
// ---------------------------------------------------------------------------
__global__ void xw1_kernel(const float* __restrict__ x,
                           const float* __restrict__ W1,
                           float* __restrict__ y, int N) {
    __shared__ float W1s[128 * 16];
    __shared__ float xs[16][128];
    int tid = threadIdx.x;
    const float4* W14 = (const float4*)W1;
    float4* W1s4 = (float4*)W1s;
    for (int i = tid; i < 512; i += 256) W1s4[i] = W14[i];
    int nblk = blockIdx.x * 16;
    const float4* x4 = (const float4*)x;
    float4* xs4 = (float4*)&xs[0][0];
    for (int i = tid; i < 512; i += 256) {
        int row = nblk + (i >> 5);
        xs4[i] = (row < N) ? x4[(size_t)row * 32 + (i & 31)]
                           : make_float4(0.f, 0.f, 0.f, 0.f);
    }
    __syncthreads();
    int nl = tid >> 4, j = tid & 15;
    int n = nblk + nl;
    if (n >= N) return;
    float acc = 0.f;
    const float* xr = &xs[nl][0];
    #pragma unroll 8
    for (int k = 0; k < 128; ++k) acc += xr[k] * W1s[k * 16 + j];
    y[(size_t)n * 16 + j] = acc;
}

// ---------------------------------------------------------------------------
// Bucket binning (unchanged from R8): LDS-staged so global writes are
// bucket-ordered runs, one global atomic per (block,bucket).
// ---------------------------------------------------------------------------
__global__ void __launch_bounds__(1024)
bucket_bin_kernel(const int* __restrict__ src, const int* __restrict__ dst,
                  int* __restrict__ bc,          // [NBKT] cursors (pre-zeroed)
                  int* __restrict__ bdst,        // [NBKT*BKT_CAP]
                  int* __restrict__ bsrc,        // [NBKT*BKT_CAP]
                  int E) {
    __shared__ int hist[NBKT], lstart[NBKT], lcur[NBKT], gbase[NBKT];
    __shared__ int sd[P1_EDGES], ss[P1_EDGES];
    int tid = threadIdx.x;
    if (tid < NBKT) { hist[tid] = 0; lcur[tid] = 0; }
    __syncthreads();

    int base = blockIdx.x * P1_EDGES + tid * 4;
    int d[4], s[4], cnt = 0;
    if (base + 3 < E) {
        int4 dd = *(const int4*)(dst + base);
        int4 sv = *(const int4*)(src + base);
        d[0] = dd.x; d[1] = dd.y; d[2] = dd.z; d[3] = dd.w;
        s[0] = sv.x; s[1] = sv.y; s[2] = sv.z; s[3] = sv.w;
        cnt = 4;
    } else {
        for (int e = base; e < E; ++e) { d[cnt] = dst[e]; s[cnt] = src[e]; ++cnt; }
    }
    for (int i = 0; i < cnt; ++i) atomicAdd(&hist[d[i] / RANGE], 1);
    __syncthreads();

    int v = (tid < NBKT) ? hist[tid] : 0;
    if (tid < NBKT) lstart[tid] = v;
    __syncthreads();
    for (int off = 1; off < NBKT; off <<= 1) {
        int t = 0;
        if (tid < NBKT && tid >= off) t = lstart[tid - off];
        __syncthreads();
        if (tid < NBKT) lstart[tid] += t;
        __syncthreads();
    }
    if (tid < NBKT) {
        lstart[tid] -= v;                                    // exclusive
        gbase[tid] = tid * BKT_CAP + atomicAdd(&bc[tid], v); // region reservation
    }
    __syncthreads();

    for (int i = 0; i < cnt; ++i) {
        int b = d[i] / RANGE;
        int r = atomicAdd(&lcur[b], 1);
        int p = lstart[b] + r;
        sd[p] = d[i]; ss[p] = s[i];
    }
    __syncthreads();

    int tot = lstart[NBKT - 1] + hist[NBKT - 1];
    for (int i = tid; i < tot; i += 1024) {
        int dv = sd[i];
        int b = dv / RANGE;
        int g = gbase[b] + (i - lstart[b]);
        bdst[g] = dv;
        bsrc[g] = ss[i];
    }
}

// ---------------------------------------------------------------------------
// Layer-1 aggregate DIRECTLY from buckets: one block per bucket.
// Random accumulation lands in LDS (ds_add_f32, stride-17 rows to spread
// banks); degree counted in the same loop. No CSR, no scan, no sort pass 2.
// Epilogue: h1 = relu((acc + y_self) * inv + b1); invdeg stored.
// ---------------------------------------------------------------------------
__global__ void __launch_bounds__(1024)
agg1b_kernel(const int* __restrict__ bc,
             const int* __restrict__ bdst,
             const int* __restrict__ bsrc,
             const float4* __restrict__ y4,   // [N][4]
             const float* __restrict__ b1,    // [16]
             const float* __restrict__ y,     // [N][16] scalar view
             float* __restrict__ h1,          // [N][16]
             float* __restrict__ invdeg, int N) {
    __shared__ float acc[RANGE][17];
    __shared__ int degc[RANGE];
    int tid = threadIdx.x;
    for (int i = tid; i < RANGE * 17; i += 1024) (&acc[0][0])[i] = 0.f;
    if (tid < RANGE) degc[tid] = 0;
    __syncthreads();

    int b = blockIdx.x;
    int m = bc[b], base_node = b * RANGE;
    const int* bd = bdst + b * BKT_CAP;
    const int* bs = bsrc + b * BKT_CAP;
    int slot = tid >> 2, q = tid & 3;        // 256 edge-slots x 4 feature-lanes
    for (int k = slot; k < m; k += 256) {
        int n = bd[k] - base_node;           // 4 lanes broadcast-read same addr
        int s = bs[k];
        float4 v = y4[(size_t)s * 4 + q];    // 16B of the 64B row per lane
        atomicAdd(&acc[n][q * 4 + 0], v.x);
        atomicAdd(&acc[n][q * 4 + 1], v.y);
        atomicAdd(&acc[n][q * 4 + 2], v.z);
        atomicAdd(&acc[n][q * 4 + 3], v.w);
        if (q == 0) atomicAdd(&degc[n], 1);
    }
    __syncthreads();

    for (int i = tid; i < RANGE * 16; i += 1024) {
        int n = i >> 4, c = i & 15;
        int node = base_node + n;
        if (node >= N) continue;
        float inv = 1.0f / (float)(degc[n] + 1);
        float val = fmaf(acc[n][c] + y[(size_t)node * 16 + c], inv, b1[c]);
        h1[(size_t)node * 16 + c] = val > 0.f ? val : 0.f;
        if (c == 0) invdeg[node] = inv;
    }
}

// ---------------------------------------------------------------------------
// Layer-2 aggregate + fused score projections, same per-bucket structure:
// g = (acc + h1_self) * invdeg;  su = g@CA;  sv = g@CB.
// ---------------------------------------------------------------------------
__global__ void __launch_bounds__(1024)
agg2b_kernel(const int* __restrict__ bc,
             const int* __restrict__ bdst,
             const int* __restrict__ bsrc,
             const float4* __restrict__ h14,  // [N][4]
             const float* __restrict__ h1,    // [N][16] scalar view
             const float* __restrict__ invdeg,
             const float* __restrict__ CA,    // [16][16]
             const float* __restrict__ CB,    // [16][16]
             float* __restrict__ su,          // [N][16]
             float* __restrict__ sv, int N) {
    __shared__ float acc[RANGE][17];
    __shared__ float g[RANGE][17];
    __shared__ float CAs[256], CBs[256];
    int tid = threadIdx.x;
    for (int i = tid; i < RANGE * 17; i += 1024) (&acc[0][0])[i] = 0.f;
    if (tid < 256) { CAs[tid] = CA[tid]; CBs[tid] = CB[tid]; }
    __syncthreads();

    int b = blockIdx.x;
    int m = bc[b], base_node = b * RANGE;
    const int* bd = bdst + b * BKT_CAP;
    const int* bs = bsrc + b * BKT_CAP;
    int slot = tid >> 2, q = tid & 3;
    for (int k = slot; k < m; k += 256) {
        int n = bd[k] - base_node;
        int s = bs[k];
        float4 v = h14[(size_t)s * 4 + q];
        atomicAdd(&acc[n][q * 4 + 0], v.x);
        atomicAdd(&acc[n][q * 4 + 1], v.y);
        atomicAdd(&acc[n][q * 4 + 2], v.z);
        atomicAdd(&acc[n][q * 4 + 3], v.w);
    }
    __syncthreads();

    for (int i = tid; i < RANGE * 16; i += 1024) {
        int n = i >> 4, c = i & 15;
        int node = base_node + n;
        g[n][c] = (node < N)
            ? (acc[n][c] + h1[(size_t)node * 16 + c]) * invdeg[node] : 0.f;
    }
    __syncthreads();

    for (int i = tid; i < RANGE * 16; i += 1024) {
        int n = i >> 4, c = i & 15;
        int node = base_node + n;
        if (node >= N) continue;
        float sa = 0.f, sb = 0.f;
        #pragma unroll
        for (int j = 0; j < 16; ++j) {
            float gj = g[n][j];
            sa += gj * CAs[j * 16 + c];
            sb += gj * CBs[j * 16 + c];
        }
        su[(size_t)node * 16 + c] = sa;
        sv[(size_t)node * 16 + c] = sb;
    }
}

// ---------------------------------------------------------------------------
// Final per-edge score: one thread per edge, full 64B row store.
// ---------------------------------------------------------------------------
__global__ void score_kernel(const int* __restrict__ src,
                             const int* __restrict__ dst,
                             const float4* __restrict__ su4,
                             const float4* __restrict__ sv4,
                             const float* __restrict__ cbias,
                             float4* __restrict__ out4, int E) {
    int e = blockIdx.x * 256 + threadIdx.x;
    if (e >= E) return;
    int s = src[e], d = dst[e];
    const float4* cb4 = (const float4*)cbias;
    #pragma unroll
    for (int q = 0; q < 4; ++q) {
        float4 a = su4[(size_t)s * 4 + q];
        float4 b = sv4[(size_t)d * 4 + q];
        float4 cb = cb4[q];
        float4 r;
        r.x = a.x + b.x + cb.x;
        r.y = a.y + b.y + cb.y;
        r.z = a.z + b.z + cb.z;
        r.w = a.w + b.w + cb.w;
        out4[(size_t)e * 4 + q] = r;
    }
}

// ---------------------------------------------------------------------------
extern "C" void kernel_launch(void* const* d_in, const int* in_sizes, int n_in,
                              void* d_out, int out_size, void* d_ws, size_t ws_size,
                              hipStream_t stream) {
    const float* x    = (const float*)d_in[0];
    const int*   src  = (const int*)  d_in[1];
    const int*   dst  = (const int*)  d_in[2];
    const float* W1   = (const float*)d_in[3];
    const float* b1   = (const float*)d_in[4];
    const float* W2   = (const float*)d_in[5];
    const float* b2   = (const float*)d_in[6];
    const float* Wmlp = (const float*)d_in[7];
    const float* bmlp = (const float*)d_in[8];
    float* out = (float*)d_out;

    const int N = in_sizes[0] / IN_F;   // 50000
    const int E = in_sizes[1];          // 800000

    // Workspace (4-byte units). bc first -> single tiny memset.
    int* bc   = (int*)d_ws;                       // NBKT
    int* bdst = bc + NBKT;                        // NBKT*BKT_CAP
    int* bsrc = bdst + NBKT * BKT_CAP;            // NBKT*BKT_CAP
    size_t intcnt = (size_t)NBKT + 2 * (size_t)NBKT * BKT_CAP;  // multiple of 4
    float* y      = (float*)d_ws + intcnt;        // N*16 (16B aligned)
    float* h1     = y + (size_t)N * 16;           // N*16
    float* su     = h1 + (size_t)N * 16;          // N*16
    float* sv     = su + (size_t)N * 16;          // N*16
    float* invdeg = sv + (size_t)N * 16;          // N (N%4==0 keeps cbias aligned)
    float* CA     = invdeg + N;                   // 256
    float* CB     = CA + 256;                     // 256
    float* cbias  = CB + 256;                     // 16

    hipMemsetAsync(bc, 0, NBKT * sizeof(int), stream);

    const int p1Blocks     = (E + P1_EDGES - 1) / P1_EDGES;  // 196
    const int edgeBlocks   = (E + 255) / 256;                // 3125
    const int nodeBlocks16 = (N + 15) / 16;                  // 3125

    precompute_kernel<<<1, 256, 0, stream>>>(W2, b2, Wmlp, bmlp, CA, CB, cbias);
    xw1_kernel<<<nodeBlocks16, 256, 0, stream>>>(x, W1, y, N);
    bucket_bin_kernel<<<p1Blocks, 1024, 0, stream>>>(src, dst, bc, bdst, bsrc, E);
    agg1b_kernel<<<NBKT, 1024, 0, stream>>>(bc, bdst, bsrc, (const float4*)y,
                                            b1, y, h1, invdeg, N);
    agg2b_kernel<<<NBKT, 1024, 0, stream>>>(bc, bdst, bsrc, (const float4*)h1,
                                            h1, invdeg, CA, CB, su, sv, N);
    score_kernel<<<edgeBlocks, 256, 0, stream>>>(src, dst, (const float4*)su,
                                                 (const float4*)sv, cbias,
                                                 (float4*)out, E);
}

// Round 12
// 199.913 us; speedup vs baseline: 1.5140x; 1.5140x over previous
//
#include <hip/hip_runtime.h>

#define IN_F 128
#define HID  16

// Bucket geometry: 256 buckets x 196 nodes covers N=50000.
// Bucket edge count ~ Binom(800k, 196/50k): mean 3136, sd ~56 -> CAP 4096 = +17 sigma.
#define NBKT 256
#define RANGE 196
#define BKT_CAP 4096
#define P1_EDGES 4096   // edges per pass-1 block (1024 threads x 4)

// ---------------------------------------------------------------------------
// Tiny precompute: CA = W2 @ Wmlp[:128], CB = W2 @ Wmlp[128:],
// cbias = b2@Wmlp[:128] + b2@Wmlp[128:] + bmlp.
// ---------------------------------------------------------------------------
__global__ void precompute_kernel(const float* __restrict__ W2,
                                  const float* __restrict__ b2,
                                  const float* __restrict__ Wmlp,
                                  const float* __restrict__ bmlp,
                                  float* __restrict__ CA,
                                  float* __restrict__ CB,
                                  float* __restrict__ cbias) {
    int t = threadIdx.x;
    int j = t >> 4, c = t & 15;
    float sa = 0.f, sb = 0.f;
    for (int k = 0; k < 128; ++k) {
        float w = W2[j * 128 + k];
        sa += w * Wmlp[k * 16 + c];
        sb += w * Wmlp[(128 + k) * 16 + c];
    }
    CA[j * 16 + c] = sa;
    CB[j * 16 + c] = sb;
    if (j == 0) {
        float s = bmlp[c];
        for (int k = 0; k < 128; ++k)
            s += b2[k] * (Wmlp[k * 16 + c] + Wmlp[(128 + k) * 16 + c]);
        cbias[c] = s;
    }
}

// ---------------------------------------------------------------------------
// y = x @ W1   ([N,128] @ [128,16] -> [N,16])
// ---------------------------------------------------------------------------
__global__ void xw1_kernel(const float* __restrict__ x,
                           const float* __restrict__ W1,
                           float* __restrict__ y, int N) {
    __shared__ float W1s[128 * 16];
    __shared__ float xs[16][128];
    int tid = threadIdx.x;
    const float4* W14 = (const float4*)W1;
    float4* W1s4 = (float4*)W1s;
    for (int i = tid; i < 512; i += 256) W1s4[i] = W14[i];
    int nblk = blockIdx.x * 16;
    const float4* x4 = (const float4*)x;
    float4* xs4 = (float4*)&xs[0][0];
    for (int i = tid; i < 512; i += 256) {
        int row = nblk + (i >> 5);
        xs4[i] = (row < N) ? x4[(size_t)row * 32 + (i & 31)]
                           : make_float4(0.f, 0.f, 0.f, 0.f);
    }
    __syncthreads();
    int nl = tid >> 4, j = tid & 15;
    int n = nblk + nl;
    if (n >= N) return;
    float acc = 0.f;
    const float* xr = &xs[nl][0];
    #pragma unroll 8
    for (int k = 0; k < 128; ++k) acc += xr[k] * W1s[k * 16 + j];
    y[(size_t)n * 16 + j] = acc;
}

// ---------------------------------------------------------------------------
// Bucket binning (proven in R8): LDS-staged so global writes are
// bucket-ordered runs, one global atomic per (block,bucket).
// ---------------------------------------------------------------------------
__global__ void __launch_bounds__(1024)
bucket_bin_kernel(const int* __restrict__ src, const int* __restrict__ dst,
                  int* __restrict__ bc,          // [NBKT] cursors (pre-zeroed)
                  int* __restrict__ bdst,        // [NBKT*BKT_CAP]
                  int* __restrict__ bsrc,        // [NBKT*BKT_CAP]
                  int E) {
    __shared__ int hist[NBKT], lstart[NBKT], lcur[NBKT], gbase[NBKT];
    __shared__ int sd[P1_EDGES], ss[P1_EDGES];
    int tid = threadIdx.x;
    if (tid < NBKT) { hist[tid] = 0; lcur[tid] = 0; }
    __syncthreads();

    int base = blockIdx.x * P1_EDGES + tid * 4;
    int d[4], s[4], cnt = 0;
    if (base + 3 < E) {
        int4 dd = *(const int4*)(dst + base);
        int4 sv = *(const int4*)(src + base);
        d[0] = dd.x; d[1] = dd.y; d[2] = dd.z; d[3] = dd.w;
        s[0] = sv.x; s[1] = sv.y; s[2] = sv.z; s[3] = sv.w;
        cnt = 4;
    } else {
        for (int e = base; e < E; ++e) { d[cnt] = dst[e]; s[cnt] = src[e]; ++cnt; }
    }
    for (int i = 0; i < cnt; ++i) atomicAdd(&hist[d[i] / RANGE], 1);
    __syncthreads();

    int v = (tid < NBKT) ? hist[tid] : 0;
    if (tid < NBKT) lstart[tid] = v;
    __syncthreads();
    for (int off = 1; off < NBKT; off <<= 1) {
        int t = 0;
        if (tid < NBKT && tid >= off) t = lstart[tid - off];
        __syncthreads();
        if (tid < NBKT) lstart[tid] += t;
        __syncthreads();
    }
    if (tid < NBKT) {
        lstart[tid] -= v;                                    // exclusive
        gbase[tid] = tid * BKT_CAP + atomicAdd(&bc[tid], v); // region reservation
    }
    __syncthreads();

    for (int i = 0; i < cnt; ++i) {
        int b = d[i] / RANGE;
        int r = atomicAdd(&lcur[b], 1);
        int p = lstart[b] + r;
        sd[p] = d[i]; ss[p] = s[i];
    }
    __syncthreads();

    int tot = lstart[NBKT - 1] + hist[NBKT - 1];
    for (int i = tid; i < tot; i += 1024) {
        int dv = sd[i];
        int b = dv / RANGE;
        int g = gbase[b] + (i - lstart[b]);
        bdst[g] = dv;
        bsrc[g] = ss[i];
    }
}

// ---------------------------------------------------------------------------
// Fused per-bucket: count -> LDS scan -> LDS scatter (local CSR) -> layer-1
// aggregate via wave-per-node GATHER (R8's proven structure, no LDS-atomic
// accumulation). Dumps sorted list + local row_ptr for agg2p.
// ---------------------------------------------------------------------------
__global__ void __launch_bounds__(1024)
sortagg1_kernel(const int* __restrict__ bc,
                const int* __restrict__ bdst,
                const int* __restrict__ bsrc,
                const float4* __restrict__ y4,   // [N][4]
                const float* __restrict__ b1,    // [16]
                int* __restrict__ bsorted,       // [NBKT*BKT_CAP]
                int* __restrict__ rlocal,        // [NBKT*(RANGE+1)]
                float4* __restrict__ h14,        // [N][4]
                float* __restrict__ invdeg, int N) {
    __shared__ int cnt[RANGE + 1];   // counts, then scatter cursors
    __shared__ int ls[RANGE + 1];    // exclusive starts, ls[RANGE]=m
    __shared__ int stage[BKT_CAP];   // sorted src ids (bucket-local)
    int tid = threadIdx.x, b = blockIdx.x;
    int base_node = b * RANGE;
    int m = bc[b];
    const int* bd = bdst + b * BKT_CAP;
    const int* bs = bsrc + b * BKT_CAP;

    if (tid <= RANGE) cnt[tid] = 0;
    __syncthreads();
    for (int i = tid; i < m; i += 1024)
        atomicAdd(&cnt[bd[i] - base_node], 1);   // 1 atomic/edge (not 16)
    __syncthreads();

    // exclusive scan of cnt[0..RANGE) -> ls (Hillis-Steele, full-block syncs)
    int v = (tid < RANGE) ? cnt[tid] : 0;
    if (tid < RANGE) ls[tid] = v;
    __syncthreads();
    for (int off = 1; off < 256; off <<= 1) {
        int t = 0;
        if (tid < RANGE && tid >= off) t = ls[tid - off];
        __syncthreads();
        if (tid < RANGE) ls[tid] += t;
        __syncthreads();
    }
    if (tid < RANGE) { int ex = ls[tid] - v; ls[tid] = ex; cnt[tid] = ex; }
    if (tid == 0) ls[RANGE] = m;
    __syncthreads();

    // scatter src ids into local sorted order (random LDS stores, 1 atomic/edge)
    for (int i = tid; i < m; i += 1024) {
        int n = bd[i] - base_node;
        int p = atomicAdd(&cnt[n], 1);
        stage[p] = bs[i];
    }
    __syncthreads();

    // persist for agg2p (coalesced)
    for (int i = tid; i < m; i += 1024) bsorted[b * BKT_CAP + i] = stage[i];
    if (tid <= RANGE) rlocal[b * (RANGE + 1) + tid] = ls[tid];

    // layer-1 aggregate: wave-per-node, 16 edge-slots x 4 float4-lanes
    int lane = tid & 63, wv = tid >> 6;
    int q = lane & 3, kk = lane >> 2;
    float4 b14 = ((const float4*)b1)[q];
    for (int r = wv; r < RANGE; r += 16) {
        int node = base_node + r;
        if (node >= N) break;                 // uniform per wave
        int beg = ls[r], end = ls[r + 1];
        float4 acc = make_float4(0.f, 0.f, 0.f, 0.f);
        if (kk == 0) acc = y4[(size_t)node * 4 + q];
        for (int k = beg + kk; k < end; k += 16) {
            int s = stage[k];                 // consecutive k -> conflict-free
            float4 vv = y4[(size_t)s * 4 + q];
            acc.x += vv.x; acc.y += vv.y; acc.z += vv.z; acc.w += vv.w;
        }
        #pragma unroll
        for (int off = 4; off < 64; off <<= 1) {
            acc.x += __shfl_xor(acc.x, off);
            acc.y += __shfl_xor(acc.y, off);
            acc.z += __shfl_xor(acc.z, off);
            acc.w += __shfl_xor(acc.w, off);
        }
        if (kk == 0) {
            float inv = 1.0f / (float)(end - beg + 1);
            float4 rr;
            rr.x = fmaxf(fmaf(acc.x, inv, b14.x), 0.f);
            rr.y = fmaxf(fmaf(acc.y, inv, b14.y), 0.f);
            rr.z = fmaxf(fmaf(acc.z, inv, b14.z), 0.f);
            rr.w = fmaxf(fmaf(acc.w, inv, b14.w), 0.f);
            h14[(size_t)node * 4 + q] = rr;
            if (q == 0) invdeg[node] = inv;
        }
    }
}

// ---------------------------------------------------------------------------
// Per-bucket layer-2 aggregate (same gather structure) + fused CA/CB
// projection: g = (h1_self + sum h1[s]) * invdeg; su = g@CA; sv = g@CB.
// ---------------------------------------------------------------------------
__global__ void __launch_bounds__(1024)
agg2p_kernel(const int* __restrict__ bsorted,
             const int* __restrict__ rlocal,
             const float4* __restrict__ h14,  // [N][4]
             const float* __restrict__ invdeg,
             const float* __restrict__ CA,    // [16][16]
             const float* __restrict__ CB,    // [16][16]
             float* __restrict__ su,          // [N][16]
             float* __restrict__ sv, int N) {
    __shared__ int ls[RANGE + 1];
    __shared__ int stage[BKT_CAP];
    __shared__ float gs[RANGE][17];
    __shared__ float CAs[256], CBs[256];
    int tid = threadIdx.x, b = blockIdx.x;
    int base_node = b * RANGE;
    if (tid <= RANGE) ls[tid] = rlocal[b * (RANGE + 1) + tid];
    if (tid < 256) { CAs[tid] = CA[tid]; CBs[tid] = CB[tid]; }
    __syncthreads();
    int m = ls[RANGE];
    for (int i = tid; i < m; i += 1024) stage[i] = bsorted[b * BKT_CAP + i];
    __syncthreads();

    int lane = tid & 63, wv = tid >> 6;
    int q = lane & 3, kk = lane >> 2;
    for (int r = wv; r < RANGE; r += 16) {
        int node = base_node + r;
        if (node >= N) break;
        int beg = ls[r], end = ls[r + 1];
        float4 acc = make_float4(0.f, 0.f, 0.f, 0.f);
        if (kk == 0) acc = h14[(size_t)node * 4 + q];
        for (int k = beg + kk; k < end; k += 16) {
            int s = stage[k];
            float4 vv = h14[(size_t)s * 4 + q];
            acc.x += vv.x; acc.y += vv.y; acc.z += vv.z; acc.w += vv.w;
        }
        #pragma unroll
        for (int off = 4; off < 64; off <<= 1) {
            acc.x += __shfl_xor(acc.x, off);
            acc.y += __shfl_xor(acc.y, off);
            acc.z += __shfl_xor(acc.z, off);
            acc.w += __shfl_xor(acc.w, off);
        }
        if (kk == 0) {
            float inv = invdeg[node];
            gs[r][q * 4 + 0] = acc.x * inv;
            gs[r][q * 4 + 1] = acc.y * inv;
            gs[r][q * 4 + 2] = acc.z * inv;
            gs[r][q * 4 + 3] = acc.w * inv;
        }
    }
    __syncthreads();

    for (int i = tid; i < RANGE * 16; i += 1024) {
        int n = i >> 4, c = i & 15;
        int node = base_node + n;
        if (node >= N) continue;
        float sa = 0.f, sb = 0.f;
        #pragma unroll
        for (int j = 0; j < 16; ++j) {
            float gj = gs[n][j];
            sa += gj * CAs[j * 16 + c];
            sb += gj * CBs[j * 16 + c];
        }
        su[(size_t)node * 16 + c] = sa;
        sv[(size_t)node * 16 + c] = sb;
    }
}

// ---------------------------------------------------------------------------
// Final per-edge score: one thread per edge, full 64B row store.
// ---------------------------------------------------------------------------
__global__ void score_kernel(const int* __restrict__ src,
                             const int* __restrict__ dst,
                             const float4* __restrict__ su4,
                             const float4* __restrict__ sv4,
                             const float* __restrict__ cbias,
                             float4* __restrict__ out4, int E) {
    int e = blockIdx.x * 256 + threadIdx.x;
    if (e >= E) return;
    int s = src[e], d = dst[e];
    const float4* cb4 = (const float4*)cbias;
    #pragma unroll
    for (int q = 0; q < 4; ++q) {
        float4 a = su4[(size_t)s * 4 + q];
        float4 b = sv4[(size_t)d * 4 + q];
        float4 cb = cb4[q];
        float4 r;
        r.x = a.x + b.x + cb.x;
        r.y = a.y + b.y + cb.y;
        r.z = a.z + b.z + cb.z;
        r.w = a.w + b.w + cb.w;
        out4[(size_t)e * 4 + q] = r;
    }
}

// ---------------------------------------------------------------------------
extern "C" void kernel_launch(void* const* d_in, const int* in_sizes, int n_in,
                              void* d_out, int out_size, void* d_ws, size_t ws_size,
                              hipStream_t stream) {
    const float* x    = (const float*)d_in[0];
    const int*   src  = (const int*)  d_in[1];
    const int*   dst  = (const int*)  d_in[2];
    const float* W1   = (const float*)d_in[3];
    const float* b1   = (const float*)d_in[4];
    const float* W2   = (const float*)d_in[5];
    const float* b2   = (const float*)d_in[6];
    const float* Wmlp = (const float*)d_in[7];
    const float* bmlp = (const float*)d_in[8];
    float* out = (float*)d_out;

    const int N = in_sizes[0] / IN_F;   // 50000
    const int E = in_sizes[1];          // 800000

    // Workspace (4-byte units). bc first -> single tiny memset.
    int* bc      = (int*)d_ws;                        // NBKT
    int* bdst    = bc + NBKT;                         // NBKT*BKT_CAP
    int* bsrc    = bdst + NBKT * BKT_CAP;             // NBKT*BKT_CAP
    int* bsorted = bsrc + NBKT * BKT_CAP;             // NBKT*BKT_CAP
    int* rlocal  = bsorted + NBKT * BKT_CAP;          // NBKT*(RANGE+1)
    size_t intcnt = (size_t)NBKT + 3 * (size_t)NBKT * BKT_CAP
                  + (size_t)NBKT * (RANGE + 1);
    intcnt = (intcnt + 3) & ~(size_t)3;               // 16B-align float region
    float* y      = (float*)d_ws + intcnt;            // N*16
    float* h1     = y + (size_t)N * 16;               // N*16
    float* su     = h1 + (size_t)N * 16;              // N*16
    float* sv     = su + (size_t)N * 16;              // N*16
    float* invdeg = sv + (size_t)N * 16;              // N (N%4==0 keeps cbias aligned)
    float* CA     = invdeg + N;                       // 256
    float* CB     = CA + 256;                         // 256
    float* cbias  = CB + 256;                         // 16

    hipMemsetAsync(bc, 0, NBKT * sizeof(int), stream);

    const int p1Blocks     = (E + P1_EDGES - 1) / P1_EDGES;  // 196
    const int edgeBlocks   = (E + 255) / 256;                // 3125
    const int nodeBlocks16 = (N + 15) / 16;                  // 3125

    precompute_kernel<<<1, 256, 0, stream>>>(W2, b2, Wmlp, bmlp, CA, CB, cbias);
    xw1_kernel<<<nodeBlocks16, 256, 0, stream>>>(x, W1, y, N);
    bucket_bin_kernel<<<p1Blocks, 1024, 0, stream>>>(src, dst, bc, bdst, bsrc, E);
    sortagg1_kernel<<<NBKT, 1024, 0, stream>>>(bc, bdst, bsrc, (const float4*)y,
                                               b1, bsorted, rlocal,
                                               (float4*)h1, invdeg, N);
    agg2p_kernel<<<NBKT, 1024, 0, stream>>>(bsorted, rlocal, (const float4*)h1,
                                            invdeg, CA, CB, su, sv, N);
    score_kernel<<<edgeBlocks, 256, 0, stream>>>(src, dst, (const float4*)su,
                                                 (const float4*)sv, cbias,
                                                 (float4*)out, E);
}

// Round 14
// 192.251 us; speedup vs baseline: 1.5744x; 1.0399x over previous
//
#include <hip/hip_runtime.h>

#define IN_F 128
#define HID  16

// Bucket geometry: 256 buckets x 196 nodes covers N=50000.
// Bucket edge count ~ Binom(800k, 196/50k): mean 3136, sd ~56 -> CAP 4096 = +17 sigma.
#define NBKT 256
#define RANGE 196
#define BKT_CAP 4096
#define P1_EDGES 4096   // edges per pass-1 block (1024 threads x 4)

// ---------------------------------------------------------------------------
// Tiny precompute: CA = W2 @ Wmlp[:128], CB = W2 @ Wmlp[128:],
// cbias = b2@Wmlp[:128] + b2@Wmlp[128:] + bmlp.
// ---------------------------------------------------------------------------
__global__ void precompute_kernel(const float* __restrict__ W2,
                                  const float* __restrict__ b2,
                                  const float* __restrict__ Wmlp,
                                  const float* __restrict__ bmlp,
                                  float* __restrict__ CA,
                                  float* __restrict__ CB,
                                  float* __restrict__ cbias) {
    int t = threadIdx.x;
    int j = t >> 4, c = t & 15;
    float sa = 0.f, sb = 0.f;
    for (int k = 0; k < 128; ++k) {
        float w = W2[j * 128 + k];
        sa += w * Wmlp[k * 16 + c];
        sb += w * Wmlp[(128 + k) * 16 + c];
    }
    CA[j * 16 + c] = sa;
    CB[j * 16 + c] = sb;
    if (j == 0) {
        float s = bmlp[c];
        for (int k = 0; k < 128; ++k)
            s += b2[k] * (Wmlp[k * 16 + c] + Wmlp[(128 + k) * 16 + c]);
        cbias[c] = s;
    }
}

// ---------------------------------------------------------------------------
// y = x @ W1   ([N,128] @ [128,16] -> [N,16])
// ---------------------------------------------------------------------------
__global__ void xw1_kernel(const float* __restrict__ x,
                           const float* __restrict__ W1,
                           float* __restrict__ y, int N) {
    __shared__ float W1s[128 * 16];
    __shared__ float xs[16][128];
    int tid = threadIdx.x;
    const float4* W14 = (const float4*)W1;
    float4* W1s4 = (float4*)W1s;
    for (int i = tid; i < 512; i += 256) W1s4[i] = W14[i];
    int nblk = blockIdx.x * 16;
    const float4* x4 = (const float4*)x;
    float4* xs4 = (float4*)&xs[0][0];
    for (int i = tid; i < 512; i += 256) {
        int row = nblk + (i >> 5);
        xs4[i] = (row < N) ? x4[(size_t)row * 32 + (i & 31)]
                           : make_float4(0.f, 0.f, 0.f, 0.f);
    }
    __syncthreads();
    int nl = tid >> 4, j = tid & 15;
    int n = nblk + nl;
    if (n >= N) return;
    float acc = 0.f;
    const float* xr = &xs[nl][0];
    #pragma unroll 8
    for (int k = 0; k < 128; ++k) acc += xr[k] * W1s[k * 16 + j];
    y[(size_t)n * 16 + j] = acc;
}

// ---------------------------------------------------------------------------
// Bucket binning: LDS-staged so global writes are bucket-ordered runs,
// one global atomic per (block,bucket). Scan single-wave (2 barriers vs 32).
// ---------------------------------------------------------------------------
__global__ void __launch_bounds__(1024)
bucket_bin_kernel(const int* __restrict__ src, const int* __restrict__ dst,
                  int* __restrict__ bc,          // [NBKT] cursors (pre-zeroed)
                  int* __restrict__ bdst,        // [NBKT*BKT_CAP]
                  int* __restrict__ bsrc,        // [NBKT*BKT_CAP]
                  int E) {
    __shared__ int hist[NBKT], lstart[NBKT], lcur[NBKT], gbase[NBKT];
    __shared__ int sd[P1_EDGES], ss[P1_EDGES];
    int tid = threadIdx.x;
    if (tid < NBKT) { hist[tid] = 0; lcur[tid] = 0; }
    __syncthreads();

    int base = blockIdx.x * P1_EDGES + tid * 4;
    int d[4], s[4], cnt = 0;
    if (base + 3 < E) {
        int4 dd = *(const int4*)(dst + base);
        int4 sv = *(const int4*)(src + base);
        d[0] = dd.x; d[1] = dd.y; d[2] = dd.z; d[3] = dd.w;
        s[0] = sv.x; s[1] = sv.y; s[2] = sv.z; s[3] = sv.w;
        cnt = 4;
    } else {
        for (int e = base; e < E; ++e) { d[cnt] = dst[e]; s[cnt] = src[e]; ++cnt; }
    }
    for (int i = 0; i < cnt; ++i) atomicAdd(&hist[d[i] / RANGE], 1);
    __syncthreads();

    // single-wave exclusive scan: wave 0, 4 entries/lane, 6 shfl_up steps
    if (tid < 64) {
        int v0 = hist[tid * 4], v1 = hist[tid * 4 + 1];
        int v2 = hist[tid * 4 + 2], v3 = hist[tid * 4 + 3];
        int s01 = v0 + v1;
        int sum = s01 + v2 + v3;
        int run = sum;
        #pragma unroll
        for (int off = 1; off < 64; off <<= 1) {
            int t = __shfl_up(run, off);
            if (tid >= off) run += t;
        }
        int excl = run - sum;
        lstart[tid * 4]     = excl;
        lstart[tid * 4 + 1] = excl + v0;
        lstart[tid * 4 + 2] = excl + s01;
        lstart[tid * 4 + 3] = excl + s01 + v2;
    }
    __syncthreads();
    if (tid < NBKT)
        gbase[tid] = tid * BKT_CAP + atomicAdd(&bc[tid], hist[tid]);
    __syncthreads();

    for (int i = 0; i < cnt; ++i) {
        int b = d[i] / RANGE;
        int r = atomicAdd(&lcur[b], 1);
        int p = lstart[b] + r;
        sd[p] = d[i]; ss[p] = s[i];
    }
    __syncthreads();

    int tot = lstart[NBKT - 1] + hist[NBKT - 1];
    for (int i = tid; i < tot; i += 1024) {
        int dv = sd[i];
        int b = dv / RANGE;
        int g = gbase[b] + (i - lstart[b]);
        bdst[g] = dv;
        bsrc[g] = ss[i];
    }
}

// ---------------------------------------------------------------------------
// Fused per-bucket: count -> wave-scan -> LDS scatter (local CSR) -> layer-1
// aggregate via wave-per-node GATHER. Dumps sorted list + local row_ptr.
// ---------------------------------------------------------------------------
__global__ void __launch_bounds__(1024)
sortagg1_kernel(const int* __restrict__ bc,
                const int* __restrict__ bdst,
                const int* __restrict__ bsrc,
                const float4* __restrict__ y4,   // [N][4]
                const float* __restrict__ b1,    // [16]
                int* __restrict__ bsorted,       // [NBKT*BKT_CAP]
                int* __restrict__ rlocal,        // [NBKT*(RANGE+1)]
                float4* __restrict__ h14,        // [N][4]
                float* __restrict__ invdeg, int N) {
    __shared__ int cnt[256];         // counts, then scatter cursors (0..195)
    __shared__ int ls[256];          // exclusive starts; ls[RANGE] == m
    __shared__ int stage[BKT_CAP];   // sorted src ids (bucket-local)
    int tid = threadIdx.x, b = blockIdx.x;
    int base_node = b * RANGE;
    int m = bc[b];
    const int* bd = bdst + b * BKT_CAP;
    const int* bs = bsrc + b * BKT_CAP;

    if (tid < 256) cnt[tid] = 0;
    __syncthreads();
    for (int i = tid; i < m; i += 1024)
        atomicAdd(&cnt[bd[i] - base_node], 1);   // 1 atomic/edge
    __syncthreads();

    // single-wave exclusive scan of cnt[0..255] -> ls (ls[196] = m naturally)
    if (tid < 64) {
        int v0 = cnt[tid * 4], v1 = cnt[tid * 4 + 1];
        int v2 = cnt[tid * 4 + 2], v3 = cnt[tid * 4 + 3];
        int s01 = v0 + v1;
        int sum = s01 + v2 + v3;
        int run = sum;
        #pragma unroll
        for (int off = 1; off < 64; off <<= 1) {
            int t = __shfl_up(run, off);
            if (tid >= off) run += t;
        }
        int excl = run - sum;
        ls[tid * 4]     = excl;
        ls[tid * 4 + 1] = excl + v0;
        ls[tid * 4 + 2] = excl + s01;
        ls[tid * 4 + 3] = excl + s01 + v2;
    }
    __syncthreads();
    if (tid < RANGE) cnt[tid] = ls[tid];         // scatter cursors
    __syncthreads();

    // scatter src ids into local sorted order (random LDS stores)
    for (int i = tid; i < m; i += 1024) {
        int n = bd[i] - base_node;
        int p = atomicAdd(&cnt[n], 1);
        stage[p] = bs[i];
    }
    __syncthreads();

    // persist for agg2p (coalesced)
    for (int i = tid; i < m; i += 1024) bsorted[b * BKT_CAP + i] = stage[i];
    if (tid <= RANGE) rlocal[b * (RANGE + 1) + tid] = ls[tid];

    // layer-1 aggregate: wave-per-node, 16 edge-slots x 4 float4-lanes
    int lane = tid & 63, wv = tid >> 6;
    int q = lane & 3, kk = lane >> 2;
    float4 b14 = ((const float4*)b1)[q];
    for (int r = wv; r < RANGE; r += 16) {
        int node = base_node + r;
        if (node >= N) break;                 // uniform per wave
        int beg = ls[r], end = ls[r + 1];
        float4 acc = make_float4(0.f, 0.f, 0.f, 0.f);
        if (kk == 0) acc = y4[(size_t)node * 4 + q];
        for (int k = beg + kk; k < end; k += 16) {
            int s = stage[k];
            float4 vv = y4[(size_t)s * 4 + q];
            acc.x += vv.x; acc.y += vv.y; acc.z += vv.z; acc.w += vv.w;
        }
        #pragma unroll
        for (int off = 4; off < 64; off <<= 1) {
            acc.x += __shfl_xor(acc.x, off);
            acc.y += __shfl_xor(acc.y, off);
            acc.z += __shfl_xor(acc.z, off);
            acc.w += __shfl_xor(acc.w, off);
        }
        if (kk == 0) {
            float inv = 1.0f / (float)(end - beg + 1);
            float4 rr;
            rr.x = fmaxf(fmaf(acc.x, inv, b14.x), 0.f);
            rr.y = fmaxf(fmaf(acc.y, inv, b14.y), 0.f);
            rr.z = fmaxf(fmaf(acc.z, inv, b14.z), 0.f);
            rr.w = fmaxf(fmaf(acc.w, inv, b14.w), 0.f);
            h14[(size_t)node * 4 + q] = rr;
            if (q == 0) invdeg[node] = inv;
        }
    }
}

// ---------------------------------------------------------------------------
// Per-bucket layer-2 aggregate (same gather structure) + fused CA/CB
// projection: g = (h1_self + sum h1[s]) * invdeg; su = g@CA; sv = g@CB.
// ---------------------------------------------------------------------------
__global__ void __launch_bounds__(1024)
agg2p_kernel(const int* __restrict__ bsorted,
             const int* __restrict__ rlocal,
             const float4* __restrict__ h14,  // [N][4]
             const float* __restrict__ invdeg,
             const float* __restrict__ CA,    // [16][16]
             const float* __restrict__ CB,    // [16][16]
             float* __restrict__ su,          // [N][16]
             float* __restrict__ sv, int N) {
    __shared__ int ls[RANGE + 1];
    __shared__ int stage[BKT_CAP];
    __shared__ float gs[RANGE][17];
    __shared__ float CAs[256], CBs[256];
    int tid = threadIdx.x, b = blockIdx.x;
    int base_node = b * RANGE;
    if (tid <= RANGE) ls[tid] = rlocal[b * (RANGE + 1) + tid];
    if (tid < 256) { CAs[tid] = CA[tid]; CBs[tid] = CB[tid]; }
    __syncthreads();
    int m = ls[RANGE];
    for (int i = tid; i < m; i += 1024) stage[i] = bsorted[b * BKT_CAP + i];
    __syncthreads();

    int lane = tid & 63, wv = tid >> 6;
    int q = lane & 3, kk = lane >> 2;
    for (int r = wv; r < RANGE; r += 16) {
        int node = base_node + r;
        if (node >= N) break;
        int beg = ls[r], end = ls[r + 1];
        float4 acc = make_float4(0.f, 0.f, 0.f, 0.f);
        if (kk == 0) acc = h14[(size_t)node * 4 + q];
        for (int k = beg + kk; k < end; k += 16) {
            int s = stage[k];
            float4 vv = h14[(size_t)s * 4 + q];
            acc.x += vv.x; acc.y += vv.y; acc.z += vv.z; acc.w += vv.w;
        }
        #pragma unroll
        for (int off = 4; off < 64; off <<= 1) {
            acc.x += __shfl_xor(acc.x, off);
            acc.y += __shfl_xor(acc.y, off);
            acc.z += __shfl_xor(acc.z, off);
            acc.w += __shfl_xor(acc.w, off);
        }
        if (kk == 0) {
            float inv = invdeg[node];
            gs[r][q * 4 + 0] = acc.x * inv;
            gs[r][q * 4 + 1] = acc.y * inv;
            gs[r][q * 4 + 2] = acc.z * inv;
            gs[r][q * 4 + 3] = acc.w * inv;
        }
    }
    __syncthreads();

    for (int i = tid; i < RANGE * 16; i += 1024) {
        int n = i >> 4, c = i & 15;
        int node = base_node + n;
        if (node >= N) continue;
        float sa = 0.f, sb = 0.f;
        #pragma unroll
        for (int j = 0; j < 16; ++j) {
            float gj = gs[n][j];
            sa += gj * CAs[j * 16 + c];
            sb += gj * CBs[j * 16 + c];
        }
        su[(size_t)node * 16 + c] = sa;
        sv[(size_t)node * 16 + c] = sb;
    }
}

// ---------------------------------------------------------------------------
// Final per-edge score: FOUR threads per edge (R7 form). Consecutive lanes
// cover the 4 quads of one edge -> every load/store instruction is contiguous
// across the wave (the R8 1-thread/edge form was per-instruction strided:
// each dwordx4 touched 64 lines/wave, 4x store transactions).
// ---------------------------------------------------------------------------
__global__ void score_kernel(const int* __restrict__ src,
                             const int* __restrict__ dst,
                             const float4* __restrict__ su4,   // [N][4]
                             const float4* __restrict__ sv4,   // [N][4]
                             const float* __restrict__ cbias,  // [16]
                             float4* __restrict__ out4,        // [E][4]
                             long long total) {                // E*4
    long long gid = (long long)blockIdx.x * 256 + threadIdx.x;
    if (gid >= total) return;
    int e = (int)(gid >> 2), c4 = (int)(gid & 3);
    float4 a = su4[(size_t)src[e] * 4 + c4];
    float4 b = sv4[(size_t)dst[e] * 4 + c4];
    const float4 cb = ((const float4*)cbias)[c4];
    float4 r;
    r.x = a.x + b.x + cb.x;
    r.y = a.y + b.y + cb.y;
    r.z = a.z + b.z + cb.z;
    r.w = a.w + b.w + cb.w;
    out4[gid] = r;
}

// ---------------------------------------------------------------------------
extern "C" void kernel_launch(void* const* d_in, const int* in_sizes, int n_in,
                              void* d_out, int out_size, void* d_ws, size_t ws_size,
                              hipStream_t stream) {
    const float* x    = (const float*)d_in[0];
    const int*   src  = (const int*)  d_in[1];
    const int*   dst  = (const int*)  d_in[2];
    const float* W1   = (const float*)d_in[3];
    const float* b1   = (const float*)d_in[4];
    const float* W2   = (const float*)d_in[5];
    const float* b2   = (const float*)d_in[6];
    const float* Wmlp = (const float*)d_in[7];
    const float* bmlp = (const float*)d_in[8];
    float* out = (float*)d_out;

    const int N = in_sizes[0] / IN_F;   // 50000
    const int E = in_sizes[1];          // 800000

    // Workspace (4-byte units). bc first -> single tiny memset.
    int* bc      = (int*)d_ws;                        // NBKT
    int* bdst    = bc + NBKT;                         // NBKT*BKT_CAP
    int* bsrc    = bdst + NBKT * BKT_CAP;             // NBKT*BKT_CAP
    int* bsorted = bsrc + NBKT * BKT_CAP;             // NBKT*BKT_CAP
    int* rlocal  = bsorted + NBKT * BKT_CAP;          // NBKT*(RANGE+1)
    size_t intcnt = (size_t)NBKT + 3 * (size_t)NBKT * BKT_CAP
                  + (size_t)NBKT * (RANGE + 1);
    intcnt = (intcnt + 3) & ~(size_t)3;               // 16B-align float region
    float* y      = (float*)d_ws + intcnt;            // N*16
    float* h1     = y + (size_t)N * 16;               // N*16
    float* su     = h1 + (size_t)N * 16;              // N*16
    float* sv     = su + (size_t)N * 16;              // N*16
    float* invdeg = sv + (size_t)N * 16;              // N (N%4==0 keeps cbias aligned)
    float* CA     = invdeg + N;                       // 256
    float* CB     = CA + 256;                         // 256
    float* cbias  = CB + 256;                         // 16

    hipMemsetAsync(bc, 0, NBKT * sizeof(int), stream);

    const long long totalE4 = (long long)E * 4;
    const int p1Blocks     = (E + P1_EDGES - 1) / P1_EDGES;  // 196
    const int edgeBlocks4  = (int)((totalE4 + 255) / 256);   // 12500
    const int nodeBlocks16 = (N + 15) / 16;                  // 3125

    precompute_kernel<<<1, 256, 0, stream>>>(W2, b2, Wmlp, bmlp, CA, CB, cbias);
    xw1_kernel<<<nodeBlocks16, 256, 0, stream>>>(x, W1, y, N);
    bucket_bin_kernel<<<p1Blocks, 1024, 0, stream>>>(src, dst, bc, bdst, bsrc, E);
    sortagg1_kernel<<<NBKT, 1024, 0, stream>>>(bc, bdst, bsrc, (const float4*)y,
                                               b1, bsorted, rlocal,
                                               (float4*)h1, invdeg, N);
    agg2p_kernel<<<NBKT, 1024, 0, stream>>>(bsorted, rlocal, (const float4*)h1,
                                            invdeg, CA, CB, su, sv, N);
    score_kernel<<<edgeBlocks4, 256, 0, stream>>>(src, dst, (const float4*)su,
                                                  (const float4*)sv, cbias,
                                                  (float4*)out, totalE4);
}